// Round 7
// baseline (721.477 us; speedup 1.0000x reference)
//
#include <hip/hip_runtime.h>

// Problem constants (match reference)
#define NX_ 432
#define NY_ 496
#define C_  64
#define B_  4
#define CELLS_ (NX_ * NY_)            // 214272 cells per (bin, batch) canvas plane
#define PLANE_ ((size_t)CELLS_)       // c-plane stride in floats
#define BATCH_STRIDE_ ((size_t)C_ * CELLS_)        // 13,713,408 floats
#define BIN_STRIDE_   ((size_t)B_ * C_ * CELLS_)   // 54,853,632 floats
#define MAP_BIN_ ((size_t)B_ * CELLS_)             // map entries per bin

#define SPLITS_ 36
#define SPAN_ (CELLS_ / SPLITS_)      // 5952 cells per block span (exact, 23808 B = 186 lines)

// native clang vector types
typedef float vfloat4 __attribute__((ext_vector_type(4)));
typedef int   vint4   __attribute__((ext_vector_type(4)));

// ---------------------------------------------------------------------------
// Kernel 1: scatter pillar index p into map[bin][b*CELLS + z + y*NX + x]
// coords layout per row: [b, z, y, x] int32. Cells are unique per sample.
// ---------------------------------------------------------------------------
__global__ __launch_bounds__(256) void scatter_idx_kernel(
    const int* __restrict__ coords0,
    const int* __restrict__ coords1,
    const int* __restrict__ coords2,
    int* __restrict__ map, int npil)
{
    const int bin = blockIdx.y;
    const int p = blockIdx.x * 256 + threadIdx.x;
    if (p >= npil) return;
    const int* coords = (bin == 0) ? coords0 : (bin == 1) ? coords1 : coords2;
    vint4 c = ((const vint4*)coords)[p];
    size_t idx = (size_t)bin * MAP_BIN_ + (size_t)c.x * CELLS_ + c.y + c.z * NX_ + c.w;
    map[idx] = p;
}

// ---------------------------------------------------------------------------
// Kernel 2: dense gather. Block = (cell split of 5952, c-HALF of 32, bin, b).
// Identical structure to R6 EXCEPT:
//   - PLAIN stores (A/B test: nontemporal suspected of sub-line write path;
//     harness fill with plain stores sustains 6.3 TB/s on this buffer)
//   - split span is 128B-aligned (5952 cells * 4B = 186 full lines), so every
//     1KB wave store covers 8 full aligned cache lines.
// ---------------------------------------------------------------------------
__global__ __launch_bounds__(256) void gather_kernel(
    const float* __restrict__ pf0,
    const float* __restrict__ pf1,
    const float* __restrict__ pf2,
    const int* __restrict__ map,
    float* __restrict__ out)
{
    const int split = blockIdx.x;        // 0..35
    const int half  = blockIdx.y;        // 0..1  (c in [half*32, half*32+32))
    const int bb    = blockIdx.z;        // 0..11 = bin*4 + b
    const int bin = bb >> 2;
    const int b   = bb & 3;

    const float* __restrict__ pf = (bin == 0) ? pf0 : (bin == 1) ? pf1 : pf2;
    const float* __restrict__ pfh = pf + half * 32;   // half-row base

    const int* mbase = map + (size_t)bin * MAP_BIN_ + (size_t)b * CELLS_
                           + (size_t)split * SPAN_;
    float* obase = out + (size_t)bin * BIN_STRIDE_ + (size_t)b * BATCH_STRIDE_
                       + (size_t)(half * 32) * PLANE_ + (size_t)split * SPAN_;

    for (int base = threadIdx.x * 4; base < SPAN_; base += 1024) {
        vint4 idx = *(const vint4*)(mbase + base);
        const bool v0 = idx.x >= 0, v1 = idx.y >= 0, v2 = idx.z >= 0, v3 = idx.w >= 0;

        // Clamp invalid to row 0 (always-safe address); 16B-aligned segment ptrs.
        const vfloat4* r0 = (const vfloat4*)(pfh + (size_t)(v0 ? idx.x : 0) * C_);
        const vfloat4* r1 = (const vfloat4*)(pfh + (size_t)(v1 ? idx.y : 0) * C_);
        const vfloat4* r2 = (const vfloat4*)(pfh + (size_t)(v2 ? idx.z : 0) * C_);
        const vfloat4* r3 = (const vfloat4*)(pfh + (size_t)(v3 ? idx.w : 0) * C_);

        float* o = obase + base;

        #pragma unroll 2
        for (int c4 = 0; c4 < 8; ++c4) {
            vfloat4 a0 = r0[c4];
            vfloat4 a1 = r1[c4];
            vfloat4 a2 = r2[c4];
            vfloat4 a3 = r3[c4];
            a0 = v0 ? a0 : (vfloat4)0.0f;
            a1 = v1 ? a1 : (vfloat4)0.0f;
            a2 = v2 ? a2 : (vfloat4)0.0f;
            a3 = v3 ? a3 : (vfloat4)0.0f;

            vfloat4 w0 = {a0.x, a1.x, a2.x, a3.x};
            vfloat4 w1 = {a0.y, a1.y, a2.y, a3.y};
            vfloat4 w2 = {a0.z, a1.z, a2.z, a3.z};
            vfloat4 w3 = {a0.w, a1.w, a2.w, a3.w};

            float* oc = o + (size_t)(c4 * 4) * PLANE_;
            *(vfloat4*)(oc)              = w0;   // plain stores — the A/B
            *(vfloat4*)(oc + PLANE_)     = w1;
            *(vfloat4*)(oc + 2 * PLANE_) = w2;
            *(vfloat4*)(oc + 3 * PLANE_) = w3;
        }
    }
}

extern "C" void kernel_launch(void* const* d_in, const int* in_sizes, int n_in,
                              void* d_out, int out_size, void* d_ws, size_t ws_size,
                              hipStream_t stream) {
    const float* pf0 = (const float*)d_in[0];
    const int*   co0 = (const int*)d_in[1];
    const float* pf1 = (const float*)d_in[2];
    const int*   co1 = (const int*)d_in[3];
    const float* pf2 = (const float*)d_in[4];
    const int*   co2 = (const int*)d_in[5];
    float* out = (float*)d_out;

    const int npil = in_sizes[1] / 4;   // rows in coords (B*P_PER)

    int* map = (int*)d_ws;
    const size_t map_bytes = 3 * MAP_BIN_ * sizeof(int);

    // init map to -1 (0xFFFFFFFF) — ~10 MB
    (void)hipMemsetAsync(map, 0xFF, map_bytes, stream);

    dim3 g1((npil + 255) / 256, 3, 1);
    scatter_idx_kernel<<<g1, 256, 0, stream>>>(co0, co1, co2, map, npil);

    dim3 g2(SPLITS_, 2, 12);   // cell-splits x c-halves x (bin*B + b)
    gather_kernel<<<g2, 256, 0, stream>>>(pf0, pf1, pf2, map, out);
}